// Round 8
// baseline (3014.980 us; speedup 1.0000x reference)
//
#include <hip/hip_runtime.h>

typedef __attribute__((ext_vector_type(8))) _Float16 f16x8;
typedef __attribute__((ext_vector_type(4))) _Float16 f16x4;
typedef __attribute__((ext_vector_type(4))) float f32x4;
typedef __attribute__((ext_vector_type(2))) unsigned int u32x2;

#define B_SZ 64
#define T_SZ 512
#define I_SZ 512
#define H_SZ 1024
#define G4   4096
#define NBLK 256

// ---------- prep: transpose + gate-interleave weights ----------
// src: [R][1024] fp32 (gate q's U or V). dst: [4096][R] f16, dst[4*n+q][r] = src[r][n]
__global__ void trans_kernel(const float* __restrict__ src, _Float16* __restrict__ dst,
                             int R, int q) {
  __shared__ float tile[64][65];
  const int n0 = blockIdx.x * 64;
  const int r0 = blockIdx.y * 64;
  const int x = threadIdx.x & 63, y = threadIdx.x >> 6;
  #pragma unroll
  for (int it = 0; it < 16; ++it) {
    int r = y * 16 + it;
    tile[r][x] = src[(size_t)(r0 + r) * H_SZ + n0 + x];
  }
  __syncthreads();
  #pragma unroll
  for (int it = 0; it < 16; ++it) {
    int rn = y * 16 + it;
    dst[(size_t)(4 * (n0 + rn) + q) * R + r0 + x] = (_Float16)tile[x][rn];
  }
}

// ---------- prep: interleave bias ----------
__global__ void bias_kernel(const float* __restrict__ b0, const float* __restrict__ b1,
                            const float* __restrict__ b2, const float* __restrict__ b3,
                            float* __restrict__ dst) {
  int g = blockIdx.x * blockDim.x + threadIdx.x;
  if (g >= G4) return;
  int q = g & 3, n = g >> 2;
  const float* s = (q == 0) ? b0 : (q == 1) ? b1 : (q == 2) ? b2 : b3;
  dst[g] = s[n];
}

__device__ __forceinline__ float h2f(unsigned short u) {
  union { unsigned short s; _Float16 h; } c; c.s = u; return (float)c.h;
}
__device__ __forceinline__ unsigned short f2h(float f) {
  union { unsigned short s; _Float16 h; } c; c.h = (_Float16)f; return c.s;
}

// x prefetch: all 256 threads, 8x16B f32 chunks, linear source (coalesced)
__device__ __forceinline__ void x_issue(const float* x, int b0, int tid, int t, f32x4* xst) {
  #pragma unroll
  for (int j = 0; j < 8; ++j) {
    const int byteoff = j * 4096 + tid * 16;   // f32-slice byte offset
    const int row  = byteoff >> 11;            // 2048 B per f32 row
    const int colb = byteoff & 2047;
    const char* sp = (const char*)x + (((size_t)(b0 + row) * T_SZ + t) * I_SZ) * 4 + colb;
    asm volatile("global_load_dwordx4 %0, %1, off" : "=v"(xst[j]) : "v"(sp) : "memory");
  }
}
// cvt f32->f16 once at stage time; write 8B chunks, XOR-swizzled (16B granules)
__device__ __forceinline__ void x_write(char* xl, int tid, const f32x4* xst) {
  #pragma unroll
  for (int j = 0; j < 8; ++j) {
    const int byteoff = j * 4096 + tid * 16;
    const int row  = byteoff >> 11;
    const int colb = (byteoff & 2047) >> 1;    // f16 byte offset, 8B-aligned
    f16x4 v = { (_Float16)xst[j].x, (_Float16)xst[j].y,
                (_Float16)xst[j].z, (_Float16)xst[j].w };
    *(f16x4*)(xl + (row << 10) + (colb ^ ((row & 7) << 4))) = v;
  }
}

// ---------- persistent recurrence ----------
// 256 blocks x 256 thr, 1/CU. blk = hgrp*4 + bgrp -> chain bgrp pinned to XCD
// pair {bgrp, bgrp+4}. Weights asm-pinned in VGPR/AGPR for all 512 steps.
// h crosses XCDs via LLC (sc0 sc1); x f16-staged in LDS dbuf (prefetch 1 ahead);
// sync = 64 per-producer flags, wave-0 poll FIRST (VMEM-quiet), flag by wave 1.
__global__ __launch_bounds__(256, 1) void lstm_recur(
    const float* __restrict__ x,        // [B][T][I] fp32
    const _Float16* __restrict__ Ubt,   // [4096][512]  row 4n+q = U_q[:,n]
    const _Float16* __restrict__ Vt,    // [4096][1024] row 4n+q = V_q[:,n]
    const float* __restrict__ biasw,    // [4096] interleaved
    float* __restrict__ out,            // hidden_seq | h_T | c_T
    _Float16* __restrict__ hbuf,        // [2][64][1024] f16 double buffer
    unsigned* __restrict__ bar)         // flags: chain bgrp at bar + bgrp*256
{
  __shared__ __align__(16) char hsh[32768];    // h slice [16][1024] f16, swizzled
  __shared__ __align__(16) char xlds[32768];   // x dbuf [2][16][512] f16, swizzled

  const int tid  = threadIdx.x;
  const int wv   = tid >> 6;
  const int lane = tid & 63;
  const int lc   = lane & 15;     // col-in-wave / A-row sel
  const int lk   = lane >> 4;     // k-group
  const int q    = lc & 3;        // gate id (0=i,1=f,2=g,3=o)
  const int p    = lc >> 2;       // quad id
  const int blk  = blockIdx.x;
  const int bgrp = blk & 3;       // batch chain (XCD pair)
  const int hgrp = blk >> 2;      // 0..63
  const int col0 = hgrp * 64 + wv * 16;
  const int b0   = bgrp * 16;
  const int sw   = (lc & 7) << 4; // read-side swizzle

  unsigned* flags = bar + bgrp * 256;   // 64 dwords per chain

  // ---- stationary weights: load once, pin via opaque asm ----
  f16x8 bU[16];
  f16x8 bV[32];
  {
    const _Float16* up = Ubt + (size_t)(col0 + lc) * I_SZ + lk * 8;
    #pragma unroll
    for (int ks = 0; ks < 16; ++ks) bU[ks] = *(const f16x8*)(up + ks * 32);
    const _Float16* vp = Vt + (size_t)(col0 + lc) * H_SZ + lk * 8;
    #pragma unroll
    for (int ks = 0; ks < 32; ++ks) bV[ks] = *(const f16x8*)(vp + ks * 32);
  }
  #pragma unroll
  for (int ks = 0; ks < 16; ++ks) asm volatile("" : "+v"(bU[ks]));
  #pragma unroll
  for (int ks = 0; ks < 32; ++ks) asm volatile("" : "+v"(bV[ks]));

  const float bias_v = biasw[col0 + lc];
  const int n_glob = hgrp * 16 + wv * 4 + p;
  const int cb     = hgrp * 16 + wv * 4;
  const size_t HO = (size_t)B_SZ * T_SZ * H_SZ;
  const size_t CO = HO + (size_t)B_SZ * H_SZ;

  float cst[4] = {0.f, 0.f, 0.f, 0.f};

  // ---- prime x(0) into xlds[0] ----
  f32x4 xst[8];
  x_issue(x, b0, tid, 0, xst);
  asm volatile("s_waitcnt vmcnt(0)" ::: "memory");
  __builtin_amdgcn_sched_barrier(0);
  x_write(xlds, tid, xst);
  __syncthreads();

#define XPROJ(ks) { \
    const f16x8 a_ = *(const f16x8*)(xl_cur + (lc << 10) + ((((ks) * 64) + lk * 16) ^ sw)); \
    acc[(ks) & 3] = __builtin_amdgcn_mfma_f32_16x16x32_f16(a_, bU[(ks)], acc[(ks) & 3], 0, 0, 0); }

  for (int t = 0; t < T_SZ; ++t) {
    const _Float16* hcur  = hbuf + (size_t)(t & 1) * (B_SZ * H_SZ);
    _Float16*       hnext = hbuf + (size_t)((t + 1) & 1) * (B_SZ * H_SZ);
    char* xl_cur = xlds + (size_t)(t & 1) * 16384;
    char* xl_nxt = xlds + (size_t)((t + 1) & 1) * 16384;

    // ---- poll FIRST: wave 0 (VMEM-quiet) checks all 64 producer flags ----
    if (t) {
      if (wv == 0) {
        const unsigned* fp = flags + lane;
        unsigned v;
        do {
          asm volatile("global_load_dword %0, %1, off sc0 sc1\n\ts_waitcnt vmcnt(0)"
                       : "=&v"(v) : "v"(fp) : "memory");
        } while (__any(v < (unsigned)t));
      }
      __syncthreads();
      __builtin_amdgcn_sched_barrier(0);
    }

    // ---- issue x(t+1) prefetch (in flight across the whole step) ----
    if (t + 1 < T_SZ) x_issue(x, b0, tid, t + 1, xst);

    // ---- issue h(t) gather from LLC (latency hidden under x-proj) ----
    f16x8 st0, st1, st2, st3, st4, st5, st6, st7;
    {
      const char* src = (const char*)(hcur + (size_t)b0 * H_SZ) + tid * 16;
      asm volatile("global_load_dwordx4 %0, %1, off sc0 sc1" : "=v"(st0) : "v"(src)          : "memory");
      asm volatile("global_load_dwordx4 %0, %1, off sc0 sc1" : "=v"(st1) : "v"(src + 4096)   : "memory");
      asm volatile("global_load_dwordx4 %0, %1, off sc0 sc1" : "=v"(st2) : "v"(src + 8192)   : "memory");
      asm volatile("global_load_dwordx4 %0, %1, off sc0 sc1" : "=v"(st3) : "v"(src + 12288)  : "memory");
      asm volatile("global_load_dwordx4 %0, %1, off sc0 sc1" : "=v"(st4) : "v"(src + 16384)  : "memory");
      asm volatile("global_load_dwordx4 %0, %1, off sc0 sc1" : "=v"(st5) : "v"(src + 20480)  : "memory");
      asm volatile("global_load_dwordx4 %0, %1, off sc0 sc1" : "=v"(st6) : "v"(src + 24576)  : "memory");
      asm volatile("global_load_dwordx4 %0, %1, off sc0 sc1" : "=v"(st7) : "v"(src + 28672)  : "memory");
    }

    f32x4 acc[4];
    acc[0] = f32x4{bias_v, bias_v, bias_v, bias_v};
    acc[1] = f32x4{0.f, 0.f, 0.f, 0.f};
    acc[2] = f32x4{0.f, 0.f, 0.f, 0.f};
    acc[3] = f32x4{0.f, 0.f, 0.f, 0.f};

    // ---- x projection from LDS f16 (hides gather + prefetch latency) ----
    #pragma unroll
    for (int ks = 0; ks < 16; ++ks) XPROJ(ks);

    // ---- drain gather + x prefetch; stage h and x(t+1) into LDS ----
    asm volatile("s_waitcnt vmcnt(0)" ::: "memory");
    __builtin_amdgcn_sched_barrier(0);
    {
      f16x8 st[8] = {st0, st1, st2, st3, st4, st5, st6, st7};
      #pragma unroll
      for (int j = 0; j < 8; ++j) {
        const int byteoff = j * 4096 + tid * 16;
        const int row  = byteoff >> 11;
        const int colb = byteoff & 2047;
        *(f16x8*)(hsh + ((row << 11) | (colb ^ ((row & 7) << 4)))) = st[j];
      }
      if (t + 1 < T_SZ) x_write(xl_nxt, tid, xst);
    }
    __syncthreads();

    // ---- h projection from LDS ----
    #pragma unroll
    for (int ks = 0; ks < 32; ++ks) {
      const int a = (lc << 11) | ((lk * 16 + ks * 64) ^ sw);
      const f16x8 hv = *(const f16x8*)(hsh + a);
      acc[ks & 3] = __builtin_amdgcn_mfma_f32_16x16x32_f16(hv, bV[ks], acc[ks & 3], 0, 0, 0);
    }

    // ---- gates ----
    float hnf[4];
    #pragma unroll
    for (int r = 0; r < 4; ++r) {
      const float v  = acc[0][r] + acc[1][r] + acc[2][r] + acc[3][r];
      const float sc = (q == 2) ? 2.f : 1.f;
      const float s  = 1.f / (1.f + __expf(-sc * v));
      const float av = (q == 2) ? (2.f * s - 1.f) : s;   // tanh via 2*sigm(2x)-1
      const float x1 = __shfl_xor(av, 1);
      const float x2 = __shfl_xor(av, 2);
      const float x3 = __shfl_xor(av, 3);
      const float gi = (q == 0) ? av : (q == 1) ? x1 : (q == 2) ? x2 : x3;
      const int m1 = q ^ 1;
      const float gf = (m1 == 0) ? av : (m1 == 1) ? x1 : (m1 == 2) ? x2 : x3;
      const int m2 = q ^ 2;
      const float gg = (m2 == 0) ? av : (m2 == 1) ? x1 : (m2 == 2) ? x2 : x3;
      const int m3 = q ^ 3;
      const float go = (m3 == 0) ? av : (m3 == 1) ? x1 : (m3 == 2) ? x2 : x3;
      const float cn = gf * cst[r] + gi * gg;
      const float s2 = 1.f / (1.f + __expf(-2.f * cn));
      hnf[r] = go * (2.f * s2 - 1.f);
      cst[r] = cn;
    }

    // ---- 4x4 shuffle transpose: lane p -> row (b0+lk*4+p), cols cb..cb+3 ----
    const unsigned c01 = (unsigned)f2h(hnf[0]) | ((unsigned)f2h(hnf[1]) << 16);
    const unsigned c23 = (unsigned)f2h(hnf[2]) | ((unsigned)f2h(hnf[3]) << 16);
    const unsigned t01 = __shfl_xor(c01, 4);
    const unsigned t23 = __shfl_xor(c23, 4);
    unsigned r01, r23;
    if (p & 1) { r01 = (t01 >> 16) | (c01 & 0xffff0000u); r23 = (t23 >> 16) | (c23 & 0xffff0000u); }
    else       { r01 = (c01 & 0xffffu) | (t01 << 16);     r23 = (c23 & 0xffffu) | (t23 << 16); }
    const unsigned x01 = __shfl_xor(r01, 8);
    const unsigned x23 = __shfl_xor(r23, 8);
    u32x2 hw;
    if (p < 2) { hw.x = r01; hw.y = x01; }
    else       { hw.x = x23; hw.y = r23; }

    const int row = b0 + lk * 4 + p;

    // ---- publish h, drain, flag (wave 1 -> wave 0 stays VMEM-quiet) ----
    if (q == 0 && t < T_SZ - 1) {
      _Float16* hp2 = hnext + (size_t)row * H_SZ + cb;
      asm volatile("global_store_dwordx2 %0, %1, off sc0 sc1" :: "v"(hp2), "v"(hw) : "memory");
    }
    asm volatile("s_waitcnt vmcnt(0)" ::: "memory");
    __syncthreads();
    if (t < T_SZ - 1 && tid == 64) {
      const unsigned* fp = flags + hgrp;
      unsigned tv = (unsigned)(t + 1);
      asm volatile("global_store_dword %0, %1, off sc0 sc1" :: "v"(fp), "v"(tv) : "memory");
    }

    // ---- hidden_seq store (drains under next step's stage vmcnt) ----
    if (q == 0) {
      f32x4 of = { h2f((unsigned short)(hw.x & 0xffffu)), h2f((unsigned short)(hw.x >> 16)),
                   h2f((unsigned short)(hw.y & 0xffffu)), h2f((unsigned short)(hw.y >> 16)) };
      *(f32x4*)(out + (size_t)row * (T_SZ * H_SZ) + (size_t)t * H_SZ + cb) = of;
      if (t == T_SZ - 1) {
        #pragma unroll
        for (int r = 0; r < 4; ++r) {
          const int b = b0 + lk * 4 + r;
          out[HO + (size_t)b * H_SZ + n_glob] = hnf[r];
          out[CO + (size_t)b * H_SZ + n_glob] = cst[r];
        }
      }
    }
  }
#undef XPROJ
}

extern "C" void kernel_launch(void* const* d_in, const int* in_sizes, int n_in,
                              void* d_out, int out_size, void* d_ws, size_t ws_size,
                              hipStream_t stream) {
  const float* x = (const float*)d_in[0];
  const float* U[4]  = {(const float*)d_in[1], (const float*)d_in[4],
                        (const float*)d_in[7], (const float*)d_in[10]};
  const float* V[4]  = {(const float*)d_in[2], (const float*)d_in[5],
                        (const float*)d_in[8], (const float*)d_in[11]};
  const float* bb[4] = {(const float*)d_in[3], (const float*)d_in[6],
                        (const float*)d_in[9], (const float*)d_in[12]};
  float* out = (float*)d_out;

  char* p = (char*)d_ws;
  _Float16* Ubt = (_Float16*)p; p += (size_t)G4 * I_SZ * 2;          // 4 MB
  _Float16* Vt  = (_Float16*)p; p += (size_t)G4 * H_SZ * 2;          // 8 MB
  float*    biasw = (float*)p;  p += (size_t)G4 * 4;                 // 16 KB
  _Float16* hbuf  = (_Float16*)p; p += (size_t)2 * B_SZ * H_SZ * 2;  // 256 KB
  unsigned* bar   = (unsigned*)p;                                    // 16 KB

  for (int qq = 0; qq < 4; ++qq)
    hipLaunchKernelGGL(trans_kernel, dim3(16, 8), dim3(256), 0, stream, U[qq], Ubt, I_SZ, qq);
  for (int qq = 0; qq < 4; ++qq)
    hipLaunchKernelGGL(trans_kernel, dim3(16, 16), dim3(256), 0, stream, V[qq], Vt, H_SZ, qq);
  hipLaunchKernelGGL(bias_kernel, dim3(16), dim3(256), 0, stream, bb[0], bb[1], bb[2], bb[3], biasw);

  // h(0) = 0 (buffer 0 read at t=0); flags = 0 (graph-replay safe)
  hipMemsetAsync(hbuf, 0, (size_t)B_SZ * H_SZ * 2, stream);
  hipMemsetAsync(bar, 0, 16384, stream);

  hipLaunchKernelGGL(lstm_recur, dim3(NBLK), dim3(256), 0, stream,
                     x, Ubt, Vt, biasw, out, hbuf, bar);
}

// Round 9
// 2265.798 us; speedup vs baseline: 1.3306x; 1.3306x over previous
//
#include <hip/hip_runtime.h>

typedef __attribute__((ext_vector_type(8))) _Float16 f16x8;
typedef __attribute__((ext_vector_type(4))) _Float16 f16x4;
typedef __attribute__((ext_vector_type(4))) float f32x4;
typedef __attribute__((ext_vector_type(2))) unsigned int u32x2;

#define B_SZ 64
#define T_SZ 512
#define I_SZ 512
#define H_SZ 1024
#define G4   4096
#define NBLK 256

// ---------- prep: transpose + gate-interleave weights ----------
// src: [R][1024] fp32 (gate q's U or V). dst: [4096][R] f16, dst[4*n+q][r] = src[r][n]
__global__ void trans_kernel(const float* __restrict__ src, _Float16* __restrict__ dst,
                             int R, int q) {
  __shared__ float tile[64][65];
  const int n0 = blockIdx.x * 64;
  const int r0 = blockIdx.y * 64;
  const int x = threadIdx.x & 63, y = threadIdx.x >> 6;
  #pragma unroll
  for (int it = 0; it < 16; ++it) {
    int r = y * 16 + it;
    tile[r][x] = src[(size_t)(r0 + r) * H_SZ + n0 + x];
  }
  __syncthreads();
  #pragma unroll
  for (int it = 0; it < 16; ++it) {
    int rn = y * 16 + it;
    dst[(size_t)(4 * (n0 + rn) + q) * R + r0 + x] = (_Float16)tile[x][rn];
  }
}

// ---------- prep: interleave bias ----------
__global__ void bias_kernel(const float* __restrict__ b0, const float* __restrict__ b1,
                            const float* __restrict__ b2, const float* __restrict__ b3,
                            float* __restrict__ dst) {
  int g = blockIdx.x * blockDim.x + threadIdx.x;
  if (g >= G4) return;
  int q = g & 3, n = g >> 2;
  const float* s = (q == 0) ? b0 : (q == 1) ? b1 : (q == 2) ? b2 : b3;
  dst[g] = s[n];
}

__device__ __forceinline__ float h2f(unsigned short u) {
  union { unsigned short s; _Float16 h; } c; c.s = u; return (float)c.h;
}
__device__ __forceinline__ unsigned short f2h(float f) {
  union { unsigned short s; _Float16 h; } c; c.h = (_Float16)f; return c.s;
}

// x prefetch: all 256 threads, 8x16B f32 chunks, linear source (coalesced)
__device__ __forceinline__ void x_issue(const float* x, int b0, int tid, int t, f32x4* xst) {
  #pragma unroll
  for (int j = 0; j < 8; ++j) {
    const int byteoff = j * 4096 + tid * 16;   // f32-slice byte offset
    const int row  = byteoff >> 11;            // 2048 B per f32 row
    const int colb = byteoff & 2047;
    const char* sp = (const char*)x + (((size_t)(b0 + row) * T_SZ + t) * I_SZ) * 4 + colb;
    asm volatile("global_load_dwordx4 %0, %1, off" : "=v"(xst[j]) : "v"(sp) : "memory");
  }
}
// cvt f32->f16 once at stage time; write 8B chunks, XOR-swizzled (16B granules)
__device__ __forceinline__ void x_write(char* xl, int tid, const f32x4* xst) {
  #pragma unroll
  for (int j = 0; j < 8; ++j) {
    const int byteoff = j * 4096 + tid * 16;
    const int row  = byteoff >> 11;
    const int colb = (byteoff & 2047) >> 1;    // f16 byte offset, 8B-aligned
    f16x4 v = { (_Float16)xst[j].x, (_Float16)xst[j].y,
                (_Float16)xst[j].z, (_Float16)xst[j].w };
    *(f16x4*)(xl + (row << 10) + (colb ^ ((row & 7) << 4))) = v;
  }
}

// ---------- persistent recurrence ----------
// 256 blocks x 256 thr, 1/CU. blk = hgrp*4 + bgrp -> chain bgrp pinned to XCD
// pair {bgrp, bgrp+4}. Weights asm-pinned in VGPR/AGPR for all 512 steps.
// h crosses XCDs via LLC (sc0 sc1); x f16-staged in LDS dbuf (prefetch 1 ahead).
// Ordering (the round-6/8 A/B lesson): x-prefetch issue + x-proj BEFORE the
// poll (off the serial chain); post-poll path minimized with a k-split
// pipelined gather. All in-loop barriers are raw s_barrier + manual waitcnt
// (a __syncthreads would vmcnt(0)-drain the in-flight prefetch every time).
__global__ __launch_bounds__(256, 1) void lstm_recur(
    const float* __restrict__ x,        // [B][T][I] fp32
    const _Float16* __restrict__ Ubt,   // [4096][512]  row 4n+q = U_q[:,n]
    const _Float16* __restrict__ Vt,    // [4096][1024] row 4n+q = V_q[:,n]
    const float* __restrict__ biasw,    // [4096] interleaved
    float* __restrict__ out,            // hidden_seq | h_T | c_T
    _Float16* __restrict__ hbuf,        // [2][64][1024] f16 double buffer
    unsigned* __restrict__ bar)         // flags: chain bgrp at bar + bgrp*256
{
  __shared__ __align__(16) char hsh[32768];    // h slice [16][1024] f16, swizzled
  __shared__ __align__(16) char xlds[32768];   // x dbuf [2][16][512] f16, swizzled

  const int tid  = threadIdx.x;
  const int wv   = tid >> 6;
  const int lane = tid & 63;
  const int lc   = lane & 15;     // col-in-wave / A-row sel
  const int lk   = lane >> 4;     // k-group
  const int q    = lc & 3;        // gate id (0=i,1=f,2=g,3=o)
  const int p    = lc >> 2;       // quad id
  const int blk  = blockIdx.x;
  const int bgrp = blk & 3;       // batch chain (XCD pair)
  const int hgrp = blk >> 2;      // 0..63
  const int col0 = hgrp * 64 + wv * 16;
  const int b0   = bgrp * 16;
  const int sw   = (lc & 7) << 4; // read-side swizzle

  unsigned* flags = bar + bgrp * 256;   // 64 dwords per chain

  // ---- stationary weights: load once, pin via opaque asm ----
  f16x8 bU[16];
  f16x8 bV[32];
  {
    const _Float16* up = Ubt + (size_t)(col0 + lc) * I_SZ + lk * 8;
    #pragma unroll
    for (int ks = 0; ks < 16; ++ks) bU[ks] = *(const f16x8*)(up + ks * 32);
    const _Float16* vp = Vt + (size_t)(col0 + lc) * H_SZ + lk * 8;
    #pragma unroll
    for (int ks = 0; ks < 32; ++ks) bV[ks] = *(const f16x8*)(vp + ks * 32);
  }
  #pragma unroll
  for (int ks = 0; ks < 16; ++ks) asm volatile("" : "+v"(bU[ks]));
  #pragma unroll
  for (int ks = 0; ks < 32; ++ks) asm volatile("" : "+v"(bV[ks]));

  const float bias_v = biasw[col0 + lc];
  const int n_glob = hgrp * 16 + wv * 4 + p;
  const int cb     = hgrp * 16 + wv * 4;
  const size_t HO = (size_t)B_SZ * T_SZ * H_SZ;
  const size_t CO = HO + (size_t)B_SZ * H_SZ;

  float cst[4] = {0.f, 0.f, 0.f, 0.f};

  // gather geometry (k-split: each thread owns one h-row's full 2 KB in 8 chunks)
  const int grow = tid >> 4;            // 0..15 (batch row)
  const int gkb  = (tid & 15) * 16;     // 0..240 (k-byte base)
  const int gsw  = (grow & 7) << 4;

  // ---- prime x(0) into xlds[0] ----
  f32x4 xst[8];
  x_issue(x, b0, tid, 0, xst);
  asm volatile("s_waitcnt vmcnt(0)" ::: "memory");
  __builtin_amdgcn_sched_barrier(0);
  x_write(xlds, tid, xst);
  asm volatile("s_waitcnt lgkmcnt(0)" ::: "memory");
  __builtin_amdgcn_s_barrier();
  __builtin_amdgcn_sched_barrier(0);

#define XPROJ(ks) { \
    const f16x8 a_ = *(const f16x8*)(xl_cur + (lc << 10) + ((((ks) * 64) + lk * 16) ^ sw)); \
    acc[(ks) & 3] = __builtin_amdgcn_mfma_f32_16x16x32_f16(a_, bU[(ks)], acc[(ks) & 3], 0, 0, 0); }
#define HPROJ(ks) { \
    const f16x8 hv = *(const f16x8*)(hsh + (lc << 11) + (((lk * 16) + (ks) * 64) ^ sw)); \
    acc[(ks) & 3] = __builtin_amdgcn_mfma_f32_16x16x32_f16(hv, bV[(ks)], acc[(ks) & 3], 0, 0, 0); }

  for (int t = 0; t < T_SZ; ++t) {
    const _Float16* hcur  = hbuf + (size_t)(t & 1) * (B_SZ * H_SZ);
    _Float16*       hnext = hbuf + (size_t)((t + 1) & 1) * (B_SZ * H_SZ);
    char* xl_cur = xlds + (size_t)(t & 1) * 16384;
    char* xl_nxt = xlds + (size_t)((t + 1) & 1) * 16384;

    // ---- 1: issue x(t+1) prefetch (in flight across x-proj + poll) ----
    if (t + 1 < T_SZ) x_issue(x, b0, tid, t + 1, xst);

    f32x4 acc[4];
    acc[0] = f32x4{bias_v, bias_v, bias_v, bias_v};
    acc[1] = f32x4{0.f, 0.f, 0.f, 0.f};
    acc[2] = f32x4{0.f, 0.f, 0.f, 0.f};
    acc[3] = f32x4{0.f, 0.f, 0.f, 0.f};

    // ---- 2: x projection (pre-poll: off the serial chain, absorbs skew) ----
    #pragma unroll
    for (int ks = 0; ks < 16; ++ks) XPROJ(ks);

    // ---- 3: wave0 polls all 64 producer flags ----
    if (t) {
      if (wv == 0) {
        const unsigned* fp = flags + lane;
        unsigned v;
        do {
          asm volatile("global_load_dword %0, %1, off sc0 sc1\n\ts_waitcnt vmcnt(0)"
                       : "=&v"(v) : "v"(fp) : "memory");
        } while (__any(v < (unsigned)t));
      }
      __builtin_amdgcn_s_barrier();
      __builtin_amdgcn_sched_barrier(0);
    }

    // ---- 4: issue h(t) gather from LLC, k-split halves ----
    f16x8 st0, st1, st2, st3, st4, st5, st6, st7;
    {
      const char* src = (const char*)(hcur + (size_t)b0 * H_SZ) + grow * 2048 + gkb;
      asm volatile("global_load_dwordx4 %0, %1, off sc0 sc1" : "=v"(st0) : "v"(src)          : "memory");
      asm volatile("global_load_dwordx4 %0, %1, off sc0 sc1" : "=v"(st1) : "v"(src + 256)    : "memory");
      asm volatile("global_load_dwordx4 %0, %1, off sc0 sc1" : "=v"(st2) : "v"(src + 512)    : "memory");
      asm volatile("global_load_dwordx4 %0, %1, off sc0 sc1" : "=v"(st3) : "v"(src + 768)    : "memory");
      asm volatile("global_load_dwordx4 %0, %1, off sc0 sc1" : "=v"(st4) : "v"(src + 1024)   : "memory");
      asm volatile("global_load_dwordx4 %0, %1, off sc0 sc1" : "=v"(st5) : "v"(src + 1280)   : "memory");
      asm volatile("global_load_dwordx4 %0, %1, off sc0 sc1" : "=v"(st6) : "v"(src + 1536)   : "memory");
      asm volatile("global_load_dwordx4 %0, %1, off sc0 sc1" : "=v"(st7) : "v"(src + 1792)   : "memory");
    }

    // ---- 5: first k-half ready (vmcnt(4): prefetch is older, drains too) ----
    asm volatile("s_waitcnt vmcnt(4)" ::: "memory");
    __builtin_amdgcn_sched_barrier(0);
    *(f16x8*)(hsh + (grow << 11) + ((gkb +   0) ^ gsw)) = st0;
    *(f16x8*)(hsh + (grow << 11) + ((gkb + 256) ^ gsw)) = st1;
    *(f16x8*)(hsh + (grow << 11) + ((gkb + 512) ^ gsw)) = st2;
    *(f16x8*)(hsh + (grow << 11) + ((gkb + 768) ^ gsw)) = st3;
    asm volatile("s_waitcnt lgkmcnt(0)" ::: "memory");
    __builtin_amdgcn_s_barrier();
    __builtin_amdgcn_sched_barrier(0);

    // ---- 6: h-proj first half (overlaps second k-half still in flight) ----
    #pragma unroll
    for (int ks = 0; ks < 16; ++ks) HPROJ(ks);

    // ---- 7: second k-half + x(t+1) stage ----
    asm volatile("s_waitcnt vmcnt(0)" ::: "memory");
    __builtin_amdgcn_sched_barrier(0);
    *(f16x8*)(hsh + (grow << 11) + ((gkb + 1024) ^ gsw)) = st4;
    *(f16x8*)(hsh + (grow << 11) + ((gkb + 1280) ^ gsw)) = st5;
    *(f16x8*)(hsh + (grow << 11) + ((gkb + 1536) ^ gsw)) = st6;
    *(f16x8*)(hsh + (grow << 11) + ((gkb + 1792) ^ gsw)) = st7;
    if (t + 1 < T_SZ) x_write(xl_nxt, tid, xst);
    asm volatile("s_waitcnt lgkmcnt(0)" ::: "memory");
    __builtin_amdgcn_s_barrier();
    __builtin_amdgcn_sched_barrier(0);

    // ---- 8: h-proj second half ----
    #pragma unroll
    for (int ks = 16; ks < 32; ++ks) HPROJ(ks);

    // ---- 9: gates ----
    float hnf[4];
    #pragma unroll
    for (int r = 0; r < 4; ++r) {
      const float v  = acc[0][r] + acc[1][r] + acc[2][r] + acc[3][r];
      const float sc = (q == 2) ? 2.f : 1.f;
      const float s  = 1.f / (1.f + __expf(-sc * v));
      const float av = (q == 2) ? (2.f * s - 1.f) : s;   // tanh via 2*sigm(2x)-1
      const float x1 = __shfl_xor(av, 1);
      const float x2 = __shfl_xor(av, 2);
      const float x3 = __shfl_xor(av, 3);
      const float gi = (q == 0) ? av : (q == 1) ? x1 : (q == 2) ? x2 : x3;
      const int m1 = q ^ 1;
      const float gf = (m1 == 0) ? av : (m1 == 1) ? x1 : (m1 == 2) ? x2 : x3;
      const int m2 = q ^ 2;
      const float gg = (m2 == 0) ? av : (m2 == 1) ? x1 : (m2 == 2) ? x2 : x3;
      const int m3 = q ^ 3;
      const float go = (m3 == 0) ? av : (m3 == 1) ? x1 : (m3 == 2) ? x2 : x3;
      const float cn = gf * cst[r] + gi * gg;
      const float s2 = 1.f / (1.f + __expf(-2.f * cn));
      hnf[r] = go * (2.f * s2 - 1.f);
      cst[r] = cn;
    }

    // ---- 10: 4x4 shuffle transpose: lane p -> row (b0+lk*4+p), cols cb.. ----
    const unsigned c01 = (unsigned)f2h(hnf[0]) | ((unsigned)f2h(hnf[1]) << 16);
    const unsigned c23 = (unsigned)f2h(hnf[2]) | ((unsigned)f2h(hnf[3]) << 16);
    const unsigned t01 = __shfl_xor(c01, 4);
    const unsigned t23 = __shfl_xor(c23, 4);
    unsigned r01, r23;
    if (p & 1) { r01 = (t01 >> 16) | (c01 & 0xffff0000u); r23 = (t23 >> 16) | (c23 & 0xffff0000u); }
    else       { r01 = (c01 & 0xffffu) | (t01 << 16);     r23 = (c23 & 0xffffu) | (t23 << 16); }
    const unsigned x01 = __shfl_xor(r01, 8);
    const unsigned x23 = __shfl_xor(r23, 8);
    u32x2 hw;
    if (p < 2) { hw.x = r01; hw.y = x01; }
    else       { hw.x = x23; hw.y = r23; }

    const int row = b0 + lk * 4 + p;

    // ---- 11: publish h (LLC), drain, barrier, flag (wave 1) ----
    if (q == 0 && t < T_SZ - 1) {
      _Float16* hp2 = hnext + (size_t)row * H_SZ + cb;
      asm volatile("global_store_dwordx2 %0, %1, off sc0 sc1" :: "v"(hp2), "v"(hw) : "memory");
    }
    asm volatile("s_waitcnt vmcnt(0)" ::: "memory");
    __builtin_amdgcn_s_barrier();
    if (t < T_SZ - 1 && tid == 64) {
      const unsigned* fp = flags + hgrp;
      unsigned tv = (unsigned)(t + 1);
      asm volatile("global_store_dword %0, %1, off sc0 sc1" :: "v"(fp), "v"(tv) : "memory");
    }

    // ---- 12: hidden_seq store (plain, L2-ack'd; off the critical path) ----
    if (q == 0) {
      f32x4 of = { h2f((unsigned short)(hw.x & 0xffffu)), h2f((unsigned short)(hw.x >> 16)),
                   h2f((unsigned short)(hw.y & 0xffffu)), h2f((unsigned short)(hw.y >> 16)) };
      *(f32x4*)(out + (size_t)row * (T_SZ * H_SZ) + (size_t)t * H_SZ + cb) = of;
      if (t == T_SZ - 1) {
        #pragma unroll
        for (int r = 0; r < 4; ++r) {
          const int b = b0 + lk * 4 + r;
          out[HO + (size_t)b * H_SZ + n_glob] = hnf[r];
          out[CO + (size_t)b * H_SZ + n_glob] = cst[r];
        }
      }
    }
  }
#undef XPROJ
#undef HPROJ
}

extern "C" void kernel_launch(void* const* d_in, const int* in_sizes, int n_in,
                              void* d_out, int out_size, void* d_ws, size_t ws_size,
                              hipStream_t stream) {
  const float* x = (const float*)d_in[0];
  const float* U[4]  = {(const float*)d_in[1], (const float*)d_in[4],
                        (const float*)d_in[7], (const float*)d_in[10]};
  const float* V[4]  = {(const float*)d_in[2], (const float*)d_in[5],
                        (const float*)d_in[8], (const float*)d_in[11]};
  const float* bb[4] = {(const float*)d_in[3], (const float*)d_in[6],
                        (const float*)d_in[9], (const float*)d_in[12]};
  float* out = (float*)d_out;

  char* p = (char*)d_ws;
  _Float16* Ubt = (_Float16*)p; p += (size_t)G4 * I_SZ * 2;          // 4 MB
  _Float16* Vt  = (_Float16*)p; p += (size_t)G4 * H_SZ * 2;          // 8 MB
  float*    biasw = (float*)p;  p += (size_t)G4 * 4;                 // 16 KB
  _Float16* hbuf  = (_Float16*)p; p += (size_t)2 * B_SZ * H_SZ * 2;  // 256 KB
  unsigned* bar   = (unsigned*)p;                                    // 16 KB

  for (int qq = 0; qq < 4; ++qq)
    hipLaunchKernelGGL(trans_kernel, dim3(16, 8), dim3(256), 0, stream, U[qq], Ubt, I_SZ, qq);
  for (int qq = 0; qq < 4; ++qq)
    hipLaunchKernelGGL(trans_kernel, dim3(16, 16), dim3(256), 0, stream, V[qq], Vt, H_SZ, qq);
  hipLaunchKernelGGL(bias_kernel, dim3(16), dim3(256), 0, stream, bb[0], bb[1], bb[2], bb[3], biasw);

  // h(0) = 0 (buffer 0 read at t=0); flags = 0 (graph-replay safe)
  hipMemsetAsync(hbuf, 0, (size_t)B_SZ * H_SZ * 2, stream);
  hipMemsetAsync(bar, 0, 16384, stream);

  hipLaunchKernelGGL(lstm_recur, dim3(NBLK), dim3(256), 0, stream,
                     x, Ubt, Vt, biasw, out, hbuf, bar);
}